// Round 6
// baseline (729.340 us; speedup 1.0000x reference)
//
#include <hip/hip_runtime.h>

#define D   256
#define WR  129          // D/2 + 1
#define B   64
static constexpr long PL = (long)D * D * WR;   // one output plane: 8,454,144 floats

// ===========================================================================
// Radix-2 Stockham FFT, 256-point, one wave per transform, 4 transforms per
// block, LDS ping-pong. (verbatim from verified round-4 kernel)
// ===========================================================================
__global__ void __launch_bounds__(256) row_fft_kernel(const float* __restrict__ imgs,
                                                      float2* __restrict__ F1T) {
    __shared__ float2 Xs[4][D];
    __shared__ float2 Ys[4][D];
    __shared__ float2 tws[128];

    const int t = threadIdx.x;
    const int f = t >> 6;          // transform id within block
    const int r = t & 63;          // lane within transform
    const int blk = blockIdx.x;
    const int b   = blk >> 5;              // 32 blocks per image
    const int rp  = ((blk & 31) << 2) + f; // row pair: rows 2rp, 2rp+1

    if (t < 128) {
        float s, c;
        sincospif(-(float)t * (1.0f / 128.0f), &s, &c);
        tws[t] = make_float2(c, s);
    }

    {
        const float* r0 = imgs + ((size_t)(b * D + 2 * rp)) * D;
        const float* r1 = r0 + D;
        #pragma unroll
        for (int j = 0; j < 4; ++j) {
            const int n = r + 64 * j;
            Xs[f][n] = make_float2(r0[n], r1[n]);
        }
    }
    __syncthreads();

    float2* Xf = Xs[f];
    float2* Yf = Ys[f];
    #pragma unroll
    for (int st = 0; st < 8; ++st) {
        float2* src = (st & 1) ? Yf : Xf;
        float2* dst = (st & 1) ? Xf : Yf;
        const int sB = 1 << st;
        #pragma unroll
        for (int hh = 0; hh < 2; ++hh) {
            const int u  = r + 64 * hh;
            const int pm = u & ~(sB - 1);
            const float2 a  = src[u];
            const float2 bv = src[u + 128];
            const float2 w  = tws[pm];
            const float dx = a.x - bv.x, dy = a.y - bv.y;
            const int o = u + pm;
            dst[o]      = make_float2(a.x + bv.x, a.y + bv.y);
            dst[o + sB] = make_float2(dx * w.x - dy * w.y, dx * w.y + dy * w.x);
        }
        __syncthreads();
    }

    for (int k = r; k <= 128; k += 64) {
        const float2 zk = Xf[k];
        const float2 zm = Xf[(256 - k) & 255];
        const float4 o4 = make_float4(0.5f * (zk.x + zm.x), 0.5f * (zk.y - zm.y),
                                      0.5f * (zk.y + zm.y), -0.5f * (zk.x - zm.x));
        *(float4*)&F1T[((size_t)(b * WR + k)) * D + 2 * rp] = o4;
    }
}

__global__ void __launch_bounds__(256) col_fft_kernel(const float2* __restrict__ F1T,
                                                      const float* __restrict__ ctf,
                                                      const float* __restrict__ hwShiftAngs,
                                                      float4* __restrict__ F4) {
    __shared__ float2 Xs[4][D];
    __shared__ float2 Ys[4][D];
    __shared__ float2 tws[128];

    const int t = threadIdx.x;
    const int f = t >> 6;
    const int r = t & 63;
    const int c = blockIdx.x * 4 + f;   // b*129 + x
    const int b = c / WR;
    const int x = c - b * WR;

    if (t < 128) {
        float s, cc;
        sincospif(-(float)t * (1.0f / 128.0f), &s, &cc);
        tws[t] = make_float2(cc, s);
    }

    {
        const float2* src = F1T + (size_t)c * D;
        #pragma unroll
        for (int j = 0; j < 4; ++j) {
            const int n = r + 64 * j;
            Xs[f][n] = src[n];
        }
    }
    __syncthreads();

    float2* Xf = Xs[f];
    float2* Yf = Ys[f];
    #pragma unroll
    for (int st = 0; st < 8; ++st) {
        float2* src = (st & 1) ? Yf : Xf;
        float2* dst = (st & 1) ? Xf : Yf;
        const int sB = 1 << st;
        #pragma unroll
        for (int hh = 0; hh < 2; ++hh) {
            const int u  = r + 64 * hh;
            const int pm = u & ~(sB - 1);
            const float2 a  = src[u];
            const float2 bv = src[u + 128];
            const float2 w  = tws[pm];
            const float dx = a.x - bv.x, dy = a.y - bv.y;
            const int o = u + pm;
            dst[o]      = make_float2(a.x + bv.x, a.y + bv.y);
            dst[o + sB] = make_float2(dx * w.x - dy * w.y, dx * w.y + dy * w.x);
        }
        __syncthreads();
    }

    const float sy = hwShiftAngs[b * 2 + 0];
    const float sx = hwShiftAngs[b * 2 + 1];

    #pragma unroll
    for (int j = 0; j < 4; ++j) {
        const int tt = r + 64 * j;                 // frequency index (pre-shift)
        const int h  = (tt + D / 2) & (D - 1);     // fftshifted row
        const float ky = (float)(h - D / 2);
        const float2 z = Xf[tt];
        const float ph = -2.0f * (ky * sy + (float)x * sx) * (1.0f / (float)D);
        float ps, pc;
        sincospif(ph, &ps, &pc);
        const float ore = z.x * pc - z.y * ps;
        const float oim = z.x * ps + z.y * pc;
        const size_t o = (size_t)(b * D + h) * WR + x;
        const float cf = ctf[o];
        F4[o] = make_float4(cf * ore, cf * oim, cf * cf, 0.f);
    }
}

// ===========================================================================
// Kernel 3: LDS-tiled SCATTER, 8x8x8 tile per block. Candidate-set logic
// identical to the verified round-5 kernel; corner accumulation rewritten
// branchless (validity folded into weights; invalid corner => +0.0 to a
// clamped in-tile slot, bit-identical result since weights are >= 0).
// ===========================================================================
#define TS 8

__global__ void __launch_bounds__(256) scatter_tile_kernel(const float4* __restrict__ F4,
                                                           const float* __restrict__ rotMats,
                                                           float* __restrict__ out) {
    __shared__ float sN[512], sI[512], sW[512], sC[512];
    __shared__ float aU[B][6];      // u=(R1,R4,R7) col_y, w=(R2,R5,R8) col_x
    __shared__ int   aBase[B];
    __shared__ int   na_s;

    const int t   = threadIdx.x;
    const int tx0 = blockIdx.x * TS;
    const int ty0 = blockIdx.y * TS;
    const int tz0 = blockIdx.z * TS;

    // centered tile center
    const float cx = (float)tx0 + 3.5f;
    const float cy = (float)ty0 + 3.5f - 128.f;
    const float cz = (float)tz0 + 3.5f - 128.f;

    sN[t] = 0.f; sN[t + 256] = 0.f;
    sI[t] = 0.f; sI[t + 256] = 0.f;
    sW[t] = 0.f; sW[t + 256] = 0.f;
    sC[t] = 0.f; sC[t + 256] = 0.f;

    if (t < 64) {                     // wave 0: cull + compact
        const float* R = rotMats + t * 9;
        const float R0 = R[0], R1 = R[1], R2 = R[2];
        const float R3 = R[3], R4 = R[4], R5 = R[5];
        const float R6 = R[6], R7 = R[7], R8 = R[8];
        const float qn = R0 * cz + R3 * cy + R6 * cx;
        const float mz = 4.5f * (fabsf(R0) + fabsf(R3) + fabsf(R6));
        const float cc2 = cz * cz + cy * cy + cx * cx;
        const bool pass = (fabsf(qn) <= mz) && (cc2 <= 35683.2f);   // 188.9^2
        const unsigned long long m = __ballot(pass);
        if (t == 0) na_s = (int)__popcll(m);
        if (pass) {
            const int a = (int)__popcll(m & ((1ull << t) - 1ull));
            aU[a][0] = R1; aU[a][1] = R4; aU[a][2] = R7;
            aU[a][3] = R2; aU[a][4] = R5; aU[a][5] = R8;
            aBase[a] = t * (D * WR);
        }
    }
    __syncthreads();

    const int na    = na_s;
    const int iy    = t >> 4;        // 0..15 (ky offset in window)
    const int ix    = t & 15;        // 0..15 (kx offset in window)
    const int xlim  = min(tx0 + 7, 128) - tx0;   // 7, or less in last x-tile

    #pragma unroll 2
    for (int a = 0; a < na; ++a) {
        const float u0 = aU[a][0], u1 = aU[a][1], u2 = aU[a][2];
        const float w0 = aU[a][3], w1 = aU[a][4], w2 = aU[a][5];
        const int  base = aBase[a];

        // window centers: ky = r.u, kx = r.w (orthonormal cols); Hölder bound
        const float cu  = cz * u0 + cy * u1 + cx * u2;
        const float cw  = cz * w0 + cy * w1 + cx * w2;
        const float wky = 4.5f * (fabsf(u0) + fabsf(u1) + fabsf(u2));  // <= 7.795
        const float wkx = 4.5f * (fabsf(w0) + fabsf(w1) + fabsf(w2));
        const int ky00 = (int)ceilf(cu - wky);    // fold + window (16 wide)
        const int kx00 = (int)ceilf(cw - wkx);
        const int ky01 = (int)ceilf(-cu - wky);   // fold - window
        const int kx01 = (int)ceilf(-cw - wkx);

        #pragma unroll
        for (int p = 0; p < 2; ++p) {
            const int ky0p = p ? ky01 : ky00;
            const int kx0p = p ? kx01 : kx00;
            // skip pass if the 16x16 window misses the sample domain (uniform)
            if (ky0p > 127 || ky0p + 15 < -128 || kx0p > 128 || kx0p + 15 < 0) continue;

            const int ky = ky0p + iy;
            const int kx = kx0p + ix;
            bool ok = (ky >= -128) & (ky <= 127) & (kx >= 0) & (kx <= 128);
            if (p) // dedup: already enumerated in pass 0's integer window
                ok &= !((ky >= ky00) & (ky <= ky00 + 15) & (kx >= kx00) & (kx <= kx00 + 15));
            if (!ok) continue;

            const float kyf = (float)ky, kxf = (float)kx;
            float rz = u0 * kyf + w0 * kxf;
            float ry = u1 * kyf + w1 * kxf;
            float rx = u2 * kyf + w2 * kxf;
            const bool neg = rx < 0.f;            // Hermitian fold (round-1 rule)
            if (neg) { rz = -rz; ry = -ry; rx = -rx; }
            const float zc = rz + 128.f;
            const float yc = ry + 128.f;
            const float xc = rx;
            const float z0f = floorf(zc), y0f = floorf(yc), x0f = floorf(xc);
            const int z0 = (int)z0f, y0 = (int)y0f, x0 = (int)x0f;
            const int iz  = z0 - tz0;             // each in [-1, 8] if touching
            const int iyv = y0 - ty0;
            const int ixv = x0 - tx0;
            // quick reject: no corner lands in this tile
            if (iz < -1 || iz > 7 || iyv < -1 || iyv > 7 || ixv < -1 || ixv > xlim) continue;

            const float4 v = F4[base + (ky + 128) * WR + kx];
            const float fz = zc - z0f, fy = yc - y0f, fx = xc - x0f;
            const float vre = v.x;
            const float vim = neg ? -v.y : v.y;
            const float vcs = v.z;

            // branchless per-axis weights (invalid => 0) + clamped indices
            float wz_[2], wy_[2], wx_[2];
            int   lz_[2], ly_[2], lx_[2];
            wz_[0] = (iz  >= 0)              ? (1.f - fz) : 0.f;  lz_[0] = max(iz, 0);
            wz_[1] = (iz  <= 6)              ? fz         : 0.f;  lz_[1] = min(iz + 1, 7);
            wy_[0] = (iyv >= 0)              ? (1.f - fy) : 0.f;  ly_[0] = max(iyv, 0);
            wy_[1] = (iyv <= 6)              ? fy         : 0.f;  ly_[1] = min(iyv + 1, 7);
            wx_[0] = (ixv >= 0)              ? (1.f - fx) : 0.f;  lx_[0] = max(ixv, 0);
            wx_[1] = (ixv + 1 <= xlim)       ? fx         : 0.f;  lx_[1] = min(ixv + 1, 7);

            #pragma unroll
            for (int dz = 0; dz < 2; ++dz) {
                #pragma unroll
                for (int dy = 0; dy < 2; ++dy) {
                    const float wzy = wz_[dz] * wy_[dy];
                    const int   lzy = (lz_[dz] << 6) | (ly_[dy] << 3);
                    #pragma unroll
                    for (int dx = 0; dx < 2; ++dx) {
                        const float wgt = wzy * wx_[dx];
                        const int   li  = lzy | lx_[dx];
                        atomicAdd(&sN[li], wgt * vre);
                        atomicAdd(&sI[li], wgt * vim);
                        atomicAdd(&sW[li], wgt);
                        atomicAdd(&sC[li], wgt * vcs);
                    }
                }
            }
        }
    }
    __syncthreads();

    #pragma unroll
    for (int rr = 0; rr < 2; ++rr) {
        const int li = t + 256 * rr;
        const int xi = tx0 + (li & 7);
        if (xi > 128) continue;
        const int yi = ty0 + ((li >> 3) & 7);
        const int zi = tz0 + (li >> 6);
        const long idx = (long)zi * (D * WR) + (long)yi * WR + xi;
        out[idx]          = sN[li];
        out[PL + idx]     = sI[li];
        out[2 * PL + idx] = sW[li];
        out[3 * PL + idx] = sC[li];
    }
}

// ---------------------------------------------------------------------------
extern "C" void kernel_launch(void* const* d_in, const int* in_sizes, int n_in,
                              void* d_out, int out_size, void* d_ws, size_t ws_size,
                              hipStream_t stream) {
    const float* imgs    = (const float*)d_in[0];   // [B, D, D]
    const float* ctf     = (const float*)d_in[1];   // [B, D, WR]
    const float* rotMats = (const float*)d_in[2];   // [B, 3, 3]
    const float* hw      = (const float*)d_in[3];   // [B, 2]
    float* out = (float*)d_out;                     // [4, D, D, WR]

    float2* F1T = (float2*)d_ws;                                   // [B,WR,D] complex (16.9 MB)
    float4* F4  = (float4*)((char*)d_ws + (size_t)B * D * WR * 8); // [B,D,WR] float4 (33.8 MB)

    row_fft_kernel<<<B * D / 2 / 4, 256, 0, stream>>>(imgs, F1T);
    col_fft_kernel<<<B * WR / 4, 256, 0, stream>>>(F1T, ctf, hw, F4);

    dim3 grid((WR + TS - 1) / TS, D / TS, D / TS);   // 17 x 32 x 32
    scatter_tile_kernel<<<grid, 256, 0, stream>>>(F4, rotMats, out);
}

// Round 7
// 573.246 us; speedup vs baseline: 1.2723x; 1.2723x over previous
//
#include <hip/hip_runtime.h>

#define D   256
#define WR  129          // D/2 + 1
#define B   64
static constexpr long PL = (long)D * D * WR;   // one output plane: 8,454,144 floats

// ===========================================================================
// Radix-2 Stockham FFT, 256-point, one wave per transform, 4 transforms per
// block, LDS ping-pong. (verbatim from verified round-4 kernel)
// ===========================================================================
__global__ void __launch_bounds__(256) row_fft_kernel(const float* __restrict__ imgs,
                                                      float2* __restrict__ F1T) {
    __shared__ float2 Xs[4][D];
    __shared__ float2 Ys[4][D];
    __shared__ float2 tws[128];

    const int t = threadIdx.x;
    const int f = t >> 6;          // transform id within block
    const int r = t & 63;          // lane within transform
    const int blk = blockIdx.x;
    const int b   = blk >> 5;              // 32 blocks per image
    const int rp  = ((blk & 31) << 2) + f; // row pair: rows 2rp, 2rp+1

    if (t < 128) {
        float s, c;
        sincospif(-(float)t * (1.0f / 128.0f), &s, &c);
        tws[t] = make_float2(c, s);
    }

    {
        const float* r0 = imgs + ((size_t)(b * D + 2 * rp)) * D;
        const float* r1 = r0 + D;
        #pragma unroll
        for (int j = 0; j < 4; ++j) {
            const int n = r + 64 * j;
            Xs[f][n] = make_float2(r0[n], r1[n]);
        }
    }
    __syncthreads();

    float2* Xf = Xs[f];
    float2* Yf = Ys[f];
    #pragma unroll
    for (int st = 0; st < 8; ++st) {
        float2* src = (st & 1) ? Yf : Xf;
        float2* dst = (st & 1) ? Xf : Yf;
        const int sB = 1 << st;
        #pragma unroll
        for (int hh = 0; hh < 2; ++hh) {
            const int u  = r + 64 * hh;
            const int pm = u & ~(sB - 1);
            const float2 a  = src[u];
            const float2 bv = src[u + 128];
            const float2 w  = tws[pm];
            const float dx = a.x - bv.x, dy = a.y - bv.y;
            const int o = u + pm;
            dst[o]      = make_float2(a.x + bv.x, a.y + bv.y);
            dst[o + sB] = make_float2(dx * w.x - dy * w.y, dx * w.y + dy * w.x);
        }
        __syncthreads();
    }

    for (int k = r; k <= 128; k += 64) {
        const float2 zk = Xf[k];
        const float2 zm = Xf[(256 - k) & 255];
        const float4 o4 = make_float4(0.5f * (zk.x + zm.x), 0.5f * (zk.y - zm.y),
                                      0.5f * (zk.y + zm.y), -0.5f * (zk.x - zm.x));
        *(float4*)&F1T[((size_t)(b * WR + k)) * D + 2 * rp] = o4;
    }
}

__global__ void __launch_bounds__(256) col_fft_kernel(const float2* __restrict__ F1T,
                                                      const float* __restrict__ ctf,
                                                      const float* __restrict__ hwShiftAngs,
                                                      float4* __restrict__ F4) {
    __shared__ float2 Xs[4][D];
    __shared__ float2 Ys[4][D];
    __shared__ float2 tws[128];

    const int t = threadIdx.x;
    const int f = t >> 6;
    const int r = t & 63;
    const int c = blockIdx.x * 4 + f;   // b*129 + x
    const int b = c / WR;
    const int x = c - b * WR;

    if (t < 128) {
        float s, cc;
        sincospif(-(float)t * (1.0f / 128.0f), &s, &cc);
        tws[t] = make_float2(cc, s);
    }

    {
        const float2* src = F1T + (size_t)c * D;
        #pragma unroll
        for (int j = 0; j < 4; ++j) {
            const int n = r + 64 * j;
            Xs[f][n] = src[n];
        }
    }
    __syncthreads();

    float2* Xf = Xs[f];
    float2* Yf = Ys[f];
    #pragma unroll
    for (int st = 0; st < 8; ++st) {
        float2* src = (st & 1) ? Yf : Xf;
        float2* dst = (st & 1) ? Xf : Yf;
        const int sB = 1 << st;
        #pragma unroll
        for (int hh = 0; hh < 2; ++hh) {
            const int u  = r + 64 * hh;
            const int pm = u & ~(sB - 1);
            const float2 a  = src[u];
            const float2 bv = src[u + 128];
            const float2 w  = tws[pm];
            const float dx = a.x - bv.x, dy = a.y - bv.y;
            const int o = u + pm;
            dst[o]      = make_float2(a.x + bv.x, a.y + bv.y);
            dst[o + sB] = make_float2(dx * w.x - dy * w.y, dx * w.y + dy * w.x);
        }
        __syncthreads();
    }

    const float sy = hwShiftAngs[b * 2 + 0];
    const float sx = hwShiftAngs[b * 2 + 1];

    #pragma unroll
    for (int j = 0; j < 4; ++j) {
        const int tt = r + 64 * j;                 // frequency index (pre-shift)
        const int h  = (tt + D / 2) & (D - 1);     // fftshifted row
        const float ky = (float)(h - D / 2);
        const float2 z = Xf[tt];
        const float ph = -2.0f * (ky * sy + (float)x * sx) * (1.0f / (float)D);
        float ps, pc;
        sincospif(ph, &ps, &pc);
        const float ore = z.x * pc - z.y * ps;
        const float oim = z.x * ps + z.y * pc;
        const size_t o = (size_t)(b * D + h) * WR + x;
        const float cf = ctf[o];
        F4[o] = make_float4(cf * ore, cf * oim, cf * cf, 0.f);
    }
}

// ===========================================================================
// Kernel 3: LDS-tiled SCATTER, 8x8x8 tile per block. Candidate-set logic
// identical to the verified round-5 kernel. Changes vs round 5:
//  - 2-copy LDS accumulator split by (ix&1): halves same-address ds_add
//    serialization from the 2x2 sample blocks that share corners.
//  - F4 load hoisted before the position math (overlaps L2 latency).
//  - per-corner "wgt > 0" guard: straight-line weight calc, zero-weight
//    corner atomics skipped (adding +0.0 is the only thing skipped).
// ===========================================================================
#define TS 8

__global__ void __launch_bounds__(256) scatter_tile_kernel(const float4* __restrict__ F4,
                                                           const float* __restrict__ rotMats,
                                                           float* __restrict__ out) {
    __shared__ float sN[1024], sI[1024], sW[1024], sC[1024];   // 2 copies each
    __shared__ float aU[B][6];      // u=(R1,R4,R7) col_y, w=(R2,R5,R8) col_x
    __shared__ int   aBase[B];
    __shared__ int   na_s;

    const int t   = threadIdx.x;
    const int tx0 = blockIdx.x * TS;
    const int ty0 = blockIdx.y * TS;
    const int tz0 = blockIdx.z * TS;

    // centered tile center
    const float cx = (float)tx0 + 3.5f;
    const float cy = (float)ty0 + 3.5f - 128.f;
    const float cz = (float)tz0 + 3.5f - 128.f;

    #pragma unroll
    for (int rr = 0; rr < 4; ++rr) {
        const int li = t + 256 * rr;
        sN[li] = 0.f; sI[li] = 0.f; sW[li] = 0.f; sC[li] = 0.f;
    }

    if (t < 64) {                     // wave 0: cull + compact
        const float* R = rotMats + t * 9;
        const float R0 = R[0], R1 = R[1], R2 = R[2];
        const float R3 = R[3], R4 = R[4], R5 = R[5];
        const float R6 = R[6], R7 = R[7], R8 = R[8];
        const float qn = R0 * cz + R3 * cy + R6 * cx;
        const float mz = 4.5f * (fabsf(R0) + fabsf(R3) + fabsf(R6));
        const float cc2 = cz * cz + cy * cy + cx * cx;
        const bool pass = (fabsf(qn) <= mz) && (cc2 <= 35683.2f);   // 188.9^2
        const unsigned long long m = __ballot(pass);
        if (t == 0) na_s = (int)__popcll(m);
        if (pass) {
            const int a = (int)__popcll(m & ((1ull << t) - 1ull));
            aU[a][0] = R1; aU[a][1] = R4; aU[a][2] = R7;
            aU[a][3] = R2; aU[a][4] = R5; aU[a][5] = R8;
            aBase[a] = t * (D * WR);
        }
    }
    __syncthreads();

    const int na    = na_s;
    const int iy    = t >> 4;        // 0..15 (ky offset in window)
    const int ix    = t & 15;        // 0..15 (kx offset in window)
    const int cofs  = (ix & 1) << 9; // accumulator copy: even/odd ix
    const int xlim  = min(tx0 + 7, 128) - tx0;   // 7, or less in last x-tile

    for (int a = 0; a < na; ++a) {
        const float u0 = aU[a][0], u1 = aU[a][1], u2 = aU[a][2];
        const float w0 = aU[a][3], w1 = aU[a][4], w2 = aU[a][5];
        const int  base = aBase[a];

        // window centers: ky = r.u, kx = r.w (orthonormal cols); Hölder bound
        const float cu  = cz * u0 + cy * u1 + cx * u2;
        const float cw  = cz * w0 + cy * w1 + cx * w2;
        const float wky = 4.5f * (fabsf(u0) + fabsf(u1) + fabsf(u2));  // <= 7.795
        const float wkx = 4.5f * (fabsf(w0) + fabsf(w1) + fabsf(w2));
        const int ky00 = (int)ceilf(cu - wky);    // fold + window (16 wide)
        const int kx00 = (int)ceilf(cw - wkx);
        const int ky01 = (int)ceilf(-cu - wky);   // fold - window
        const int kx01 = (int)ceilf(-cw - wkx);

        #pragma unroll
        for (int p = 0; p < 2; ++p) {
            const int ky0p = p ? ky01 : ky00;
            const int kx0p = p ? kx01 : kx00;
            // skip pass if the 16x16 window misses the sample domain (uniform)
            if (ky0p > 127 || ky0p + 15 < -128 || kx0p > 128 || kx0p + 15 < 0) continue;

            const int ky = ky0p + iy;
            const int kx = kx0p + ix;
            bool ok = (ky >= -128) & (ky <= 127) & (kx >= 0) & (kx <= 128);
            if (p) // dedup: already enumerated in pass 0's integer window
                ok &= !((ky >= ky00) & (ky <= ky00 + 15) & (kx >= kx00) & (kx <= kx00 + 15));
            if (!ok) continue;

            // ---- hoisted load: only needs (ky,kx); overlaps the math below
            const float4 v = F4[base + (ky + 128) * WR + kx];

            const float kyf = (float)ky, kxf = (float)kx;
            float rz = u0 * kyf + w0 * kxf;
            float ry = u1 * kyf + w1 * kxf;
            float rx = u2 * kyf + w2 * kxf;
            const bool neg = rx < 0.f;            // Hermitian fold (round-1 rule)
            if (neg) { rz = -rz; ry = -ry; rx = -rx; }
            const float zc = rz + 128.f;
            const float yc = ry + 128.f;
            const float xc = rx;
            const float z0f = floorf(zc), y0f = floorf(yc), x0f = floorf(xc);
            const int z0 = (int)z0f, y0 = (int)y0f, x0 = (int)x0f;
            const int iz  = z0 - tz0;             // each in [-1, 8] if touching
            const int iyv = y0 - ty0;
            const int ixv = x0 - tx0;
            // quick reject: no corner lands in this tile
            if (iz < -1 || iz > 7 || iyv < -1 || iyv > 7 || ixv < -1 || ixv > xlim) continue;

            const float fz = zc - z0f, fy = yc - y0f, fx = xc - x0f;
            const float vre = v.x;
            const float vim = neg ? -v.y : v.y;
            const float vcs = v.z;

            // branchless per-axis weights (out-of-tile => 0); indices only
            // consumed when the corner weight is > 0 (then clamp is identity)
            float wz_[2], wy_[2], wx_[2];
            int   lz_[2], ly_[2], lx_[2];
            wz_[0] = (iz  >= 0)        ? (1.f - fz) : 0.f;  lz_[0] = max(iz, 0);
            wz_[1] = (iz  <= 6)        ? fz         : 0.f;  lz_[1] = min(iz + 1, 7);
            wy_[0] = (iyv >= 0)        ? (1.f - fy) : 0.f;  ly_[0] = max(iyv, 0);
            wy_[1] = (iyv <= 6)        ? fy         : 0.f;  ly_[1] = min(iyv + 1, 7);
            wx_[0] = (ixv >= 0)        ? (1.f - fx) : 0.f;  lx_[0] = max(ixv, 0);
            wx_[1] = (ixv + 1 <= xlim) ? fx         : 0.f;  lx_[1] = min(ixv + 1, 7);

            #pragma unroll
            for (int dz = 0; dz < 2; ++dz) {
                #pragma unroll
                for (int dy = 0; dy < 2; ++dy) {
                    const float wzy = wz_[dz] * wy_[dy];
                    const int   lzy = cofs | (lz_[dz] << 6) | (ly_[dy] << 3);
                    #pragma unroll
                    for (int dx = 0; dx < 2; ++dx) {
                        const float wgt = wzy * wx_[dx];
                        if (wgt > 0.f) {          // skip zero-weight corners
                            const int li = lzy | lx_[dx];
                            atomicAdd(&sN[li], wgt * vre);
                            atomicAdd(&sI[li], wgt * vim);
                            atomicAdd(&sW[li], wgt);
                            atomicAdd(&sC[li], wgt * vcs);
                        }
                    }
                }
            }
        }
    }
    __syncthreads();

    #pragma unroll
    for (int rr = 0; rr < 2; ++rr) {
        const int li = t + 256 * rr;
        const int xi = tx0 + (li & 7);
        if (xi > 128) continue;
        const int yi = ty0 + ((li >> 3) & 7);
        const int zi = tz0 + (li >> 6);
        const long idx = (long)zi * (D * WR) + (long)yi * WR + xi;
        out[idx]          = sN[li] + sN[li + 512];
        out[PL + idx]     = sI[li] + sI[li + 512];
        out[2 * PL + idx] = sW[li] + sW[li + 512];
        out[3 * PL + idx] = sC[li] + sC[li + 512];
    }
}

// ---------------------------------------------------------------------------
extern "C" void kernel_launch(void* const* d_in, const int* in_sizes, int n_in,
                              void* d_out, int out_size, void* d_ws, size_t ws_size,
                              hipStream_t stream) {
    const float* imgs    = (const float*)d_in[0];   // [B, D, D]
    const float* ctf     = (const float*)d_in[1];   // [B, D, WR]
    const float* rotMats = (const float*)d_in[2];   // [B, 3, 3]
    const float* hw      = (const float*)d_in[3];   // [B, 2]
    float* out = (float*)d_out;                     // [4, D, D, WR]

    float2* F1T = (float2*)d_ws;                                   // [B,WR,D] complex (16.9 MB)
    float4* F4  = (float4*)((char*)d_ws + (size_t)B * D * WR * 8); // [B,D,WR] float4 (33.8 MB)

    row_fft_kernel<<<B * D / 2 / 4, 256, 0, stream>>>(imgs, F1T);
    col_fft_kernel<<<B * WR / 4, 256, 0, stream>>>(F1T, ctf, hw, F4);

    dim3 grid((WR + TS - 1) / TS, D / TS, D / TS);   // 17 x 32 x 32
    scatter_tile_kernel<<<grid, 256, 0, stream>>>(F4, rotMats, out);
}